// Round 9
// baseline (17290.613 us; speedup 1.0000x reference)
//
#include <hip/hip_runtime.h>
#include <cstdint>

typedef __attribute__((ext_vector_type(8))) short  short8;
typedef __attribute__((ext_vector_type(4))) float  float4v;
typedef unsigned long long u64;

__device__ __forceinline__ short bf16r(float f) {
  union { float f; uint32_t u; } v; v.f = f;
  uint32_t r = (v.u + 0x7FFFu + ((v.u >> 16) & 1u)) >> 16;   // RNE
  return (short)(uint16_t)r;
}
__device__ __forceinline__ float sig_(float x)  { return 1.f / (1.f + __expf(-x)); }
__device__ __forceinline__ float tanh_(float x) {
  x = fminf(15.f, fmaxf(-15.f, x));
  float e = __expf(-2.f * x);
  return (1.f - e) / (1.f + e);
}

// ==================== per-step-launch path ====================
#define WREG_BYTES 9437184ull            // region A: WUt bf16 [4096][1152] (St overlays later)
#define HB_BYTES   1048576ull            // h ping-pong: 2 x 256x1024 bf16
#define CB_BYTES   1048576ull            // c: 256x1024 f32
#define NEED_STEP  (WREG_BYTES + HB_BYTES + CB_BYTES)

__global__ void prep_zero(u64* hb, u64* cc, u64* outw) {
  int g = blockIdx.x * 256 + threadIdx.x;          // 16384 threads
#pragma unroll
  for (int i = 0; i < 8; ++i) hb[g + i * 16384] = 0ull;   // 1MB
#pragma unroll
  for (int i = 0; i < 8; ++i) cc[g + i * 16384] = 0ull;   // 1MB
  if (g < 768) outw[g] = 0ull;                            // 6144 f32
}

// transpose+convert weights into pre-swizzled bf16 [n][KW] (byte-in-row ^= (n&7)<<4)
__global__ void prep_weights(const float* __restrict__ A, const float* __restrict__ B,
                             short* __restrict__ dst, int KW, int enc) {
  __shared__ short tl[64][68];
  const int kt = blockIdx.x >> 6, nt = blockIdx.x & 63;
  const int tid = threadIdx.x;
  const int kl = tid >> 6, nl = tid & 63;
  for (int r = 0; r < 16; ++r) {
    int k = kt * 64 + r * 4 + kl, n = nt * 64 + nl;
    float f;
    if (enc) f = (k < 128) ? A[(size_t)k * 4096 + n] : B[(size_t)(k - 128) * 4096 + n];
    else     f = A[(size_t)k * 4096 + n] + B[(size_t)k * 4096 + n];
    tl[r * 4 + kl][nl] = bf16r(f);
  }
  __syncthreads();
  for (int i = 0; i < 4; ++i) {
    int idx = i * 256 + tid;
    int nl2 = idx >> 4, k4 = idx & 15;
    int n = nt * 64 + nl2, kb = k4 * 4;
    short4 v;
    v.x = tl[kb][nl2]; v.y = tl[kb + 1][nl2]; v.z = tl[kb + 2][nl2]; v.w = tl[kb + 3][nl2];
    uint32_t byterow = (uint32_t)(kt * 64 + kb) * 2u;
    size_t off = (size_t)n * (size_t)(KW * 2) + (size_t)(byterow ^ (uint32_t)((n & 7) << 4));
    *(short4*)((char*)dst + off) = v;
  }
}

// one LSTM step. KW=1152 encoder (x|h), KW=1024 decoder (h only, z = h@(W+U))
template<int KW, int DEC>
__global__ void __launch_bounds__(512, 1)
lstm_step(const float* __restrict__ x, int t, const short* __restrict__ Wt,
          const u64* __restrict__ hsrc, u64* __restrict__ hdst,
          float* __restrict__ cst, const float* __restrict__ bias,
          const float* __restrict__ denW, const float* __restrict__ denB,
          float* __restrict__ out, int td)
{
  extern __shared__ char smem[];                   // [B slice KW*128 | zs 16KB]
  float* zs = (float*)(smem + KW * 128);
  const int tid = threadIdx.x, wg = blockIdx.x;
  const int wgc = wg & 63, wgr = wg >> 6;          // colgroup c -> XCD c%8 every step
  const int lane = tid & 63, wv = tid >> 6;
  const int l15 = lane & 15, lq = lane >> 4;
  const int mq = wv & 1, ks = wv >> 1;

  // ---- async B-slice: pre-swizzled global -> linear LDS (row gather by n) ----
  {
    constexpr int NCH = (KW * 128) / 8192;         // wave-iters (18 or 16)
    for (int i = 0; i < NCH; ++i) {
      uint32_t base = (uint32_t)((i * 8 + wv) * 1024);
      uint32_t ldsoff = base + (uint32_t)lane * 16u;
      uint32_t rB = ldsoff / (uint32_t)(KW * 2);
      uint32_t koff = ldsoff - rB * (uint32_t)(KW * 2);
      uint32_t n = (rB >> 4) * 1024u + (uint32_t)wgc * 16u + (rB & 15u);
      const char* src = (const char*)Wt + (size_t)n * (size_t)(KW * 2) + koff;
      __builtin_amdgcn_global_load_lds(
          (const __attribute__((address_space(1))) void*)src,
          (__attribute__((address_space(3))) void*)(smem + base), 16, 0, 0);
    }
  }

  // ---- register loads (independent of LDS fill) ----
  float4v u0, u1, w0, w1;
  if constexpr (!DEC) {
    const float* xp0 = x + ((size_t)(wgr * 64 + mq * 32 + l15) * 512 + (size_t)t) * 128 + ks * 32 + lq * 8;
    const float* xp1 = xp0 + (size_t)16 * 512 * 128;
    u0 = *(const float4v*)xp0; u1 = *(const float4v*)(xp0 + 4);
    w0 = *(const float4v*)xp1; w1 = *(const float4v*)(xp1 + 4);
  }
  u64 q0[8], q1[8], q2[8], q3[8];
  {
    const char* hr0 = (const char*)hsrc + (size_t)(wgr * 64 + mq * 32 + l15) * 2048;
    const char* hr1 = hr0 + 16 * 2048;
#pragma unroll
    for (int kk = 0; kk < 8; ++kk) {
      uint32_t kb = (uint32_t)(ks * 256 + kk * 32 + lq * 8) * 2u;
      q0[kk] = *(const u64*)(hr0 + kb); q1[kk] = *(const u64*)(hr0 + kb + 8);
      q2[kk] = *(const u64*)(hr1 + kb); q3[kk] = *(const u64*)(hr1 + kb + 8);
    }
  }
  const int erow = tid >> 3, ecp = tid & 7;
  const int gcol0 = wgc * 16 + 2 * ecp, gcol1 = gcol0 + 1;
  const int growg = wgr * 64 + erow;
  const int erot = ((erow >> 2) & 3) << 4;
  const float bi0 = bias[gcol0],        bi1 = bias[gcol1];
  const float bf0 = bias[1024 + gcol0], bf1 = bias[1024 + gcol1];
  const float bg0 = bias[2048 + gcol0], bg1 = bias[2048 + gcol1];
  const float bo0 = bias[3072 + gcol0], bo1 = bias[3072 + gcol1];
  float2 cc = *(const float2*)(cst + (size_t)growg * 1024 + gcol0);
  float dw0 = 0.f, dw1 = 0.f, db = 0.f;
  if constexpr (DEC) { dw0 = denW[gcol0]; dw1 = denW[gcol1]; db = denB[0]; }

  { float* p = zs + tid * 8; float4v z = {0.f,0.f,0.f,0.f};
    *(float4v*)p = z; *(float4v*)(p + 4) = z; }

  asm volatile("s_waitcnt vmcnt(0)" ::: "memory");
  __syncthreads();

  // ---- MFMAs ----
  uint32_t bbase[4], bmask[4];
#pragma unroll
  for (int nf = 0; nf < 4; ++nf) {
    int rB = nf * 16 + l15;
    bbase[nf] = (uint32_t)((rB * KW + lq * 8) * 2);
    bmask[nf] = (uint32_t)((rB & 7) << 4);
  }
  float4v acc[2][4];
#pragma unroll
  for (int a = 0; a < 2; ++a)
#pragma unroll
    for (int b = 0; b < 4; ++b) acc[a][b] = (float4v){0.f,0.f,0.f,0.f};

  if constexpr (!DEC) {
    short8 a0, a1;
#pragma unroll
    for (int j = 0; j < 4; ++j) {
      a0[j] = bf16r(u0[j]); a0[4 + j] = bf16r(u1[j]);
      a1[j] = bf16r(w0[j]); a1[4 + j] = bf16r(w1[j]);
    }
    const uint32_t Kg = (uint32_t)(ks * 32);
#pragma unroll
    for (int nf = 0; nf < 4; ++nf) {
      short8 b = *(const short8*)(smem + ((bbase[nf] + 2u * Kg) ^ bmask[nf]));
      acc[0][nf] = __builtin_amdgcn_mfma_f32_16x16x32_bf16(a0, b, acc[0][nf], 0, 0, 0);
      acc[1][nf] = __builtin_amdgcn_mfma_f32_16x16x32_bf16(a1, b, acc[1][nf], 0, 0, 0);
    }
  }
#pragma unroll
  for (int kk = 0; kk < 8; ++kk) {
    union { u64 q[2]; short8 s; } ua, ub;
    ua.q[0] = q0[kk]; ua.q[1] = q1[kk];
    ub.q[0] = q2[kk]; ub.q[1] = q3[kk];
    const uint32_t Kw = (uint32_t)((DEC ? 0 : 128) + ks * 256 + kk * 32);
#pragma unroll
    for (int nf = 0; nf < 4; ++nf) {
      short8 b = *(const short8*)(smem + ((bbase[nf] + 2u * Kw) ^ bmask[nf]));
      acc[0][nf] = __builtin_amdgcn_mfma_f32_16x16x32_bf16(ua.s, b, acc[0][nf], 0, 0, 0);
      acc[1][nf] = __builtin_amdgcn_mfma_f32_16x16x32_bf16(ub.s, b, acc[1][nf], 0, 0, 0);
    }
  }
  // ---- K-slice reduction into zs ----
#pragma unroll
  for (int mf = 0; mf < 2; ++mf)
#pragma unroll
    for (int nf = 0; nf < 4; ++nf)
#pragma unroll
      for (int e = 0; e < 4; ++e) {
        int row = mq * 32 + mf * 16 + lq * 4 + e;
        int col = (nf * 16 + l15) ^ (lq << 4);
        atomicAdd(&zs[row * 64 + col], acc[mf][nf][e]);
      }
  __syncthreads();

  // ---- gates / state update ----
  {
    const float* zr = zs + erow * 64;
    float2 I = *(const float2*)(zr + (( 0 + 2 * ecp) ^ erot));
    float2 F = *(const float2*)(zr + ((16 + 2 * ecp) ^ erot));
    float2 G = *(const float2*)(zr + ((32 + 2 * ecp) ^ erot));
    float2 O = *(const float2*)(zr + ((48 + 2 * ecp) ^ erot));
    float cA = sig_(F.x + bf0) * cc.x + sig_(I.x + bi0) * tanh_(G.x + bg0);
    float cB = sig_(F.y + bf1) * cc.y + sig_(I.y + bi1) * tanh_(G.y + bg1);
    float hA = sig_(O.x + bo0) * tanh_(cA);
    float hB = sig_(O.y + bo1) * tanh_(cB);
    *(float2*)(cst + (size_t)growg * 1024 + gcol0) = make_float2(cA, cB);
    unsigned hp = (unsigned)(unsigned short)bf16r(hA)
                | ((unsigned)(unsigned short)bf16r(hB) << 16);
    ((unsigned*)hdst)[(size_t)growg * 512 + wgc * 8 + ecp] = hp;
    if constexpr (DEC) {
      float p = hA * dw0 + hB * dw1;
      p += __shfl_xor(p, 1); p += __shfl_xor(p, 2); p += __shfl_xor(p, 4);
      if (ecp == 0)
        atomicAdd(&out[(size_t)growg * 24 + td], p + (wgc == 0 ? db : 0.f));
    }
  }
}

// ==================== fallback: round-8 persistent kernel (ws < 11MB) ====================
#define NWG  256
#define NTHR 512
#define HBUF_U64 65536ull
#define WS_NEED_FB (HBUF_U64 * 2ull * 8ull + 1024ull)
#define BLDS_BYTES 147456
#define SMEM_BYTES (BLDS_BYTES + 16384)

#define ALD(p)    __hip_atomic_load((p), __ATOMIC_RELAXED, __HIP_MEMORY_SCOPE_AGENT)
#define AST(p, v) __hip_atomic_store((p), (v), __ATOMIC_RELAXED, __HIP_MEMORY_SCOPE_AGENT)

__device__ __forceinline__ unsigned mall_load(const unsigned* p) {
  unsigned v;
  asm volatile("global_load_dword %0, %1, off sc0 sc1\n\t"
               "s_waitcnt vmcnt(0)"
               : "=v"(v) : "v"((unsigned long long)p) : "memory");
  return v;
}
__device__ __forceinline__ void mall_store(unsigned* p, unsigned v) {
  asm volatile("global_store_dword %0, %1, off sc0 sc1"
               :: "v"((unsigned long long)p), "v"(v) : "memory");
}

__global__ void __launch_bounds__(NTHR, 1)
lstm_all(const float* __restrict__ x,
         const float* __restrict__ encW, const float* __restrict__ encU, const float* __restrict__ encB,
         const float* __restrict__ celW, const float* __restrict__ celU, const float* __restrict__ celB,
         const float* __restrict__ denW, const float* __restrict__ denB,
         float* __restrict__ out,
         u64* __restrict__ hb, unsigned* __restrict__ barp)
{
  extern __shared__ char smem[];
  float* zs = (float*)(smem + BLDS_BYTES);
  const int tid = threadIdx.x, wg = blockIdx.x;
  const int wgr = (wg & 7) >> 1;
  const int wgc = ((wg >> 3) << 1) | (wg & 1);
  unsigned* bar = barp + wgr * 64;
  unsigned syncno = 0;

  if (tid < 256)
    AST(hb + (size_t)wgc * 1024 + (size_t)wgr * 256 + tid, 0ull);
  if (wgc == 0)
    for (int i = tid; i < 768; i += NTHR)
      AST((u64*)out + (size_t)wgr * 768 + i, 0ull);

  {
    const int r = tid & 63, slot = tid >> 6;
    const int n = (r >> 4) * 1024 + wgc * 16 + (r & 15);
    for (int i = 0; i < 5; ++i) {
      int kk = slot + 8 * i;
      if (kk < 36) {
        for (int j8 = 0; j8 < 4; ++j8) {
          short8 v;
#pragma unroll
          for (int j = 0; j < 8; ++j) {
            int k = kk * 32 + j8 * 8 + j;
            float f = (k < 128) ? encW[(size_t)k * 4096 + n]
                                : encU[(size_t)(k - 128) * 4096 + n];
            v[j] = bf16r(f);
          }
          uint32_t byte = ((uint32_t)(r * 1152 + kk * 32 + j8 * 8) * 2u) ^ (uint32_t)((r & 7) << 4);
          *(short8*)(smem + byte) = v;
        }
      }
    }
  }
  const int lane = tid & 63, wv = tid >> 6;
  const int l15 = lane & 15, lq = lane >> 4;
  const int mq = wv & 1, ks = wv >> 1;
  uint32_t bbase[4], bmask[4];
#pragma unroll
  for (int nf = 0; nf < 4; ++nf) {
    int rB = nf * 16 + l15;
    bbase[nf] = (uint32_t)((rB * 1152 + lq * 8) * 2);
    bmask[nf] = (uint32_t)((rB & 7) << 4);
  }
  const int erow = tid >> 3, ecp = tid & 7;
  const int gcol0 = wgc * 16 + 2 * ecp, gcol1 = gcol0 + 1;
  const int growg = wgr * 64 + erow;
  const int erot  = ((erow >> 2) & 3) << 4;
  const float bei0 = encB[gcol0], bei1 = encB[gcol1];
  const float bef0 = encB[1024 + gcol0], bef1 = encB[1024 + gcol1];
  const float beg0 = encB[2048 + gcol0], beg1 = encB[2048 + gcol1];
  const float beo0 = encB[3072 + gcol0], beo1 = encB[3072 + gcol1];
  const float bci0 = celB[gcol0], bci1 = celB[gcol1];
  const float bcf0 = celB[1024 + gcol0], bcf1 = celB[1024 + gcol1];
  const float bcg0 = celB[2048 + gcol0], bcg1 = celB[2048 + gcol1];
  const float bco0 = celB[3072 + gcol0], bco1 = celB[3072 + gcol1];
  const float dw0 = denW[gcol0], dw1 = denW[gcol1], db = denB[0];
  float cA = 0.f, cB = 0.f;
  int cur = 0;
  float4v acc[2][4];

  auto xpart = [&](int t) {
    const int Kg = ks * 32;
    const float* xp0 = x + ((size_t)(wgr * 64 + mq * 32 + l15) * 512 + (size_t)t) * 128 + Kg + lq * 8;
    const float* xp1 = xp0 + (size_t)16 * 512 * 128;
    float4v u0 = *(const float4v*)xp0, u1 = *(const float4v*)(xp0 + 4);
    float4v w0 = *(const float4v*)xp1, w1 = *(const float4v*)(xp1 + 4);
    short8 a0, a1;
#pragma unroll
    for (int j = 0; j < 4; ++j) {
      a0[j] = bf16r(u0[j]); a0[4 + j] = bf16r(u1[j]);
      a1[j] = bf16r(w0[j]); a1[4 + j] = bf16r(w1[j]);
    }
#pragma unroll
    for (int nf = 0; nf < 4; ++nf) {
      short8 b = *(const short8*)(smem + ((bbase[nf] + 2u * (uint32_t)Kg) ^ bmask[nf]));
      acc[0][nf] = __builtin_amdgcn_mfma_f32_16x16x32_bf16(a0, b, acc[0][nf], 0, 0, 0);
      acc[1][nf] = __builtin_amdgcn_mfma_f32_16x16x32_bf16(a1, b, acc[1][nf], 0, 0, 0);
    }
  };
  auto hpart = [&](const u64* hbase, int wk0) {
    const int rbase = wgr * 64 + mq * 32 + l15;
    u64 q0[8], q1[8], q2[8], q3[8];
#pragma unroll
    for (int kk = 0; kk < 8; ++kk) {
      const int kc = ks * 256 + kk * 32;
      const int c0 = kc + lq * 8;
      const size_t bidx = (size_t)(c0 >> 4) * 1024 + (size_t)rbase * 4 + (size_t)((c0 & 15) >> 2);
      q0[kk] = ALD(hbase + bidx);      q1[kk] = ALD(hbase + bidx + 1);
      q2[kk] = ALD(hbase + bidx + 64); q3[kk] = ALD(hbase + bidx + 65);
    }
#pragma unroll
    for (int kk = 0; kk < 8; ++kk) {
      const int kc = ks * 256 + kk * 32;
      union { u64 q[2]; short8 s; } ua, ub;
      ua.q[0] = q0[kk]; ua.q[1] = q1[kk];
      ub.q[0] = q2[kk]; ub.q[1] = q3[kk];
      const uint32_t Kw = (uint32_t)(wk0 + kc);
#pragma unroll
      for (int nf = 0; nf < 4; ++nf) {
        short8 b = *(const short8*)(smem + ((bbase[nf] + 2u * Kw) ^ bmask[nf]));
        acc[0][nf] = __builtin_amdgcn_mfma_f32_16x16x32_bf16(ua.s, b, acc[0][nf], 0, 0, 0);
        acc[1][nf] = __builtin_amdgcn_mfma_f32_16x16x32_bf16(ub.s, b, acc[1][nf], 0, 0, 0);
      }
    }
  };
  auto reduce_zs = [&]() {
#pragma unroll
    for (int mf = 0; mf < 2; ++mf)
#pragma unroll
      for (int nf = 0; nf < 4; ++nf)
#pragma unroll
        for (int e = 0; e < 4; ++e) {
          int row = mq * 32 + mf * 16 + lq * 4 + e;
          int col = (nf * 16 + l15) ^ (lq << 4);
          atomicAdd(&zs[row * 64 + col], acc[mf][nf][e]);
        }
  };
  auto st_reload = [&]() {
    const int r = tid & 63, slot = tid >> 6;
    const int n = (r >> 4) * 1024 + wgc * 16 + (r & 15);
    for (int i = 0; i < 4; ++i) {
      int kk = slot + 8 * i;
      for (int j8 = 0; j8 < 4; ++j8) {
        short8 v;
#pragma unroll
        for (int j = 0; j < 8; ++j) {
          int k = kk * 32 + j8 * 8 + j;
          float f = celW[(size_t)k * 4096 + n] + celU[(size_t)k * 4096 + n];
          v[j] = bf16r(f);
        }
        uint32_t byte = ((uint32_t)(r * 1152 + kk * 32 + j8 * 8) * 2u) ^ (uint32_t)((r & 7) << 4);
        *(short8*)(smem + byte) = v;
      }
    }
  };
  auto barrier_overlap = [&](int xt, bool reload) {
    asm volatile("s_waitcnt vmcnt(0)" ::: "memory");
    __syncthreads();
    ++syncno;
    if (tid == 0) mall_store(bar + wgc, syncno);
    { float* p = zs + tid * 8; float4v zz = {0.f,0.f,0.f,0.f};
      *(float4v*)p = zz; *(float4v*)(p + 4) = zz; }
#pragma unroll
    for (int mf = 0; mf < 2; ++mf)
#pragma unroll
      for (int nf = 0; nf < 4; ++nf) acc[mf][nf] = (float4v){0.f,0.f,0.f,0.f};
    if (xt >= 0) xpart(xt);
    if (reload) st_reload();
    if (tid < 64) {
      while (mall_load(bar + tid) < syncno) __builtin_amdgcn_s_sleep(4);
    }
    __syncthreads();
  };
  auto epilogue = [&](bool dec, int td) {
    const float* zr = zs + erow * 64;
    float2 I = *(const float2*)(zr + (( 0 + 2 * ecp) ^ erot));
    float2 F = *(const float2*)(zr + ((16 + 2 * ecp) ^ erot));
    float2 G = *(const float2*)(zr + ((32 + 2 * ecp) ^ erot));
    float2 O = *(const float2*)(zr + ((48 + 2 * ecp) ^ erot));
    float i0, i1, f0, f1, g0, g1, o0, o1;
    if (!dec) { i0=I.x+bei0; i1=I.y+bei1; f0=F.x+bef0; f1=F.y+bef1;
                g0=G.x+beg0; g1=G.y+beg1; o0=O.x+beo0; o1=O.y+beo1; }
    else      { i0=I.x+bci0; i1=I.y+bci1; f0=F.x+bcf0; f1=F.y+bcf1;
                g0=G.x+bcg0; g1=G.y+bcg1; o0=O.x+bco0; o1=O.y+bco1; }
    cA = sig_(f0) * cA + sig_(i0) * tanh_(g0);
    cB = sig_(f1) * cB + sig_(i1) * tanh_(g1);
    float hA = sig_(o0) * tanh_(cA);
    float hB = sig_(o1) * tanh_(cB);
    unsigned hp = (unsigned)(unsigned short)bf16r(hA)
                | ((unsigned)(unsigned short)bf16r(hB) << 16);
    unsigned* h32 = (unsigned*)hb;
    size_t idx = (size_t)(cur ^ 1) * 131072 + (size_t)wgc * 2048 + (size_t)growg * 8 + ecp;
    AST(h32 + idx, hp);
    if (dec) {
      float p = hA * dw0 + hB * dw1;
      p += __shfl_xor(p, 1); p += __shfl_xor(p, 2); p += __shfl_xor(p, 4);
      if (ecp == 0)
        atomicAdd(&out[(size_t)growg * 24 + td], p + (wgc == 0 ? db : 0.f));
    }
  };

  barrier_overlap(0, false);
  for (int t = 0; t < 512; ++t) {
    hpart(hb + (size_t)cur * HBUF_U64, 128);
    reduce_zs();
    __syncthreads();
    epilogue(false, 0);
    cur ^= 1;
    if (t < 511) barrier_overlap(t + 1, false);
    else         barrier_overlap(-1, true);
  }
  for (int td = 0; td < 24; ++td) {
    hpart(hb + (size_t)cur * HBUF_U64, 0);
    reduce_zs();
    __syncthreads();
    epilogue(true, td);
    cur ^= 1;
    if (td < 23) barrier_overlap(-1, false);
  }
}

// ==================== launcher ====================
extern "C" void kernel_launch(void* const* d_in, const int* in_sizes, int n_in,
                              void* d_out, int out_size, void* d_ws, size_t ws_size,
                              hipStream_t stream) {
  const float* x    = (const float*)d_in[0];
  const float* encW = (const float*)d_in[1];
  const float* encU = (const float*)d_in[2];
  const float* encB = (const float*)d_in[3];
  const float* celW = (const float*)d_in[4];
  const float* celU = (const float*)d_in[5];
  const float* celB = (const float*)d_in[6];
  const float* denW = (const float*)d_in[7];
  const float* denB = (const float*)d_in[8];
  float* out = (float*)d_out;

  if (ws_size >= NEED_STEP) {
    short* Wt  = (short*)d_ws;
    u64*   hbw = (u64*)((char*)d_ws + WREG_BYTES);
    float* cst = (float*)((char*)d_ws + WREG_BYTES + HB_BYTES);
    const size_t HBUF = 65536;                       // u64 per h buffer

    hipFuncSetAttribute((const void*)lstm_step<1152,0>,
                        hipFuncAttributeMaxDynamicSharedMemorySize, 163840);
    hipFuncSetAttribute((const void*)lstm_step<1024,1>,
                        hipFuncAttributeMaxDynamicSharedMemorySize, 163840);

    prep_zero<<<64, 256, 0, stream>>>(hbw, (u64*)cst, (u64*)out);
    prep_weights<<<18 * 64, 256, 0, stream>>>(encW, encU, Wt, 1152, 1);
    for (int t = 0; t < 512; ++t) {
      const u64* hs = hbw + (size_t)(t & 1) * HBUF;
      u64*       hd = hbw + (size_t)((t + 1) & 1) * HBUF;
      lstm_step<1152,0><<<256, 512, 163840, stream>>>(
          x, t, Wt, hs, hd, cst, encB, nullptr, nullptr, nullptr, 0);
    }
    prep_weights<<<16 * 64, 256, 0, stream>>>(celW, celU, Wt, 1024, 0);
    for (int td = 0; td < 24; ++td) {
      int cur = td & 1;                              // h_enc landed in buf 0
      const u64* hs = hbw + (size_t)cur * HBUF;
      u64*       hd = hbw + (size_t)(cur ^ 1) * HBUF;
      lstm_step<1024,1><<<256, 512, 163840, stream>>>(
          nullptr, 0, Wt, hs, hd, cst, celB, denW, denB, out, td);
    }
    return;
  }

  if (ws_size < WS_NEED_FB) return;                  // visible failure, no OOB
  u64*      hb  = (u64*)d_ws;
  unsigned* bar = (unsigned*)((char*)d_ws + HBUF_U64 * 2ull * 8ull);
  hipMemsetAsync(bar, 0, 1024, stream);
  hipFuncSetAttribute((const void*)lstm_all,
                      hipFuncAttributeMaxDynamicSharedMemorySize, SMEM_BYTES);
  void* args[] = { (void*)&x, (void*)&encW, (void*)&encU, (void*)&encB,
                   (void*)&celW, (void*)&celU, (void*)&celB,
                   (void*)&denW, (void*)&denB,
                   (void*)&out, (void*)&hb, (void*)&bar };
  hipLaunchCooperativeKernel((void*)lstm_all, dim3(NWG), dim3(NTHR), args,
                             (unsigned)SMEM_BYTES, stream);
}